// Round 12
// baseline (637.924 us; speedup 1.0000x reference)
//
#include <hip/hip_runtime.h>
#include <hip/hip_fp16.h>

#define N_NODES 100000
#define N_EDGES 1600000
#define N_GRAPHS 512
#define F 128
#define N_CONVS 4
#define SCAN_NBLK ((N_NODES + 1023) / 1024)   // 98
#define FILL_BLOCKS ((N_EDGES + 255) / 256)   // 6250
#define NWIN 8
#define WIN_SZ ((N_NODES + NWIN - 1) / NWIN)

#define W2_STRIDE 132
#define W2_LAYER (128 * W2_STRIDE)

typedef __attribute__((ext_vector_type(8))) short short8;
typedef __attribute__((ext_vector_type(4))) float f32x4;

union FragU { uint4 u; short8 v; };
union HU { uint2 u; __half2 h[2]; };
union HU4 { uint4 u; __half2 h[4]; };

__device__ __forceinline__ unsigned int pack_hilo(float f) {
    unsigned int u = __float_as_uint(f);
    unsigned int hb = u & 0xFFFF0000u;
    float d = f - __uint_as_float(hb);
    unsigned int lb = __float_as_uint(d) >> 16;
    return (u >> 16) | (lb << 16);
}

__device__ __forceinline__ float4 red4(float4 a) {
    a.x += __shfl_down(a.x, 32, 64); a.y += __shfl_down(a.y, 32, 64);
    a.z += __shfl_down(a.z, 32, 64); a.w += __shfl_down(a.w, 32, 64);
    a.x += __shfl_down(a.x, 16, 64); a.y += __shfl_down(a.y, 16, 64);
    a.z += __shfl_down(a.z, 16, 64); a.w += __shfl_down(a.w, 16, 64);
    return a;
}

// ---------------- CSR build ----------------

__global__ void count_kernel(const int* __restrict__ dst, int* __restrict__ cnt) {
    int e = blockIdx.x * blockDim.x + threadIdx.x;
    if (e < N_EDGES) atomicAdd(&cnt[dst[e]], 1);
}

__global__ void dinv_kernel(const int* __restrict__ cnt, float* __restrict__ dinv) {
    int n = blockIdx.x * blockDim.x + threadIdx.x;
    if (n < N_NODES) dinv[n] = rsqrtf((float)cnt[n] + 2.0f);
}

__global__ void scan1_kernel(const int* __restrict__ cnt, int* __restrict__ excl,
                             int* __restrict__ blksum) {
    __shared__ int sums[256];
    int t = threadIdx.x;
    int base = blockIdx.x * 1024 + t * 4;
    int v0 = 0, v1 = 0, v2 = 0, v3 = 0;
    if (base + 0 < N_NODES) v0 = cnt[base + 0];
    if (base + 1 < N_NODES) v1 = cnt[base + 1];
    if (base + 2 < N_NODES) v2 = cnt[base + 2];
    if (base + 3 < N_NODES) v3 = cnt[base + 3];
    int s = v0 + v1 + v2 + v3;
    sums[t] = s;
    __syncthreads();
    for (int off = 1; off < 256; off <<= 1) {
        int y = (t >= off) ? sums[t - off] : 0;
        __syncthreads();
        sums[t] += y;
        __syncthreads();
    }
    int pre = sums[t] - s;
    if (base + 0 < N_NODES) excl[base + 0] = pre;
    if (base + 1 < N_NODES) excl[base + 1] = pre + v0;
    if (base + 2 < N_NODES) excl[base + 2] = pre + v0 + v1;
    if (base + 3 < N_NODES) excl[base + 3] = pre + v0 + v1 + v2;
    if (t == 255) blksum[blockIdx.x] = sums[255];
}

__global__ void scan2_kernel(int* __restrict__ blksum, int nblk) {
    __shared__ int sh[128];
    int t = threadIdx.x;
    int v = (t < nblk) ? blksum[t] : 0;
    sh[t] = v;
    __syncthreads();
    for (int off = 1; off < 128; off <<= 1) {
        int y = (t >= off) ? sh[t - off] : 0;
        __syncthreads();
        sh[t] += y;
        __syncthreads();
    }
    if (t < nblk) blksum[t] = sh[t] - v;
}

__global__ void scan3_kernel(int* __restrict__ rowptr, const int* __restrict__ blksum,
                             int* __restrict__ fill) {
    int t = threadIdx.x;
    int base = blockIdx.x * 1024 + t * 4;
    int off = blksum[blockIdx.x];
#pragma unroll
    for (int i = 0; i < 4; i++) {
        int idx = base + i;
        if (idx < N_NODES) {
            int v = rowptr[idx] + off;
            rowptr[idx] = v;
            fill[idx] = v;
        }
    }
    if (blockIdx.x == 0 && t == 0) rowptr[N_NODES] = N_EDGES;
}

// ---------------- XCD-windowed CSR fill (best measured variant) ----------------

__global__ __launch_bounds__(256) void fillw_kernel(
        const int* __restrict__ src, const int* __restrict__ dst,
        const float* __restrict__ dinv, int* __restrict__ fill,
        int2* __restrict__ edges) {
    int b = blockIdx.x;
    int w = b & (NWIN - 1);
    int e = (b >> 3) * 256 + threadIdx.x;
    if (e < N_EDGES) {
        int d = dst[e];
        if (d / WIN_SZ == w) {
            int s = src[e];
            int pos = atomicAdd(&fill[d], 1);
            edges[pos] = make_int2(s, __float_as_int(dinv[s] * dinv[d]));
        }
    }
}

// ---------------- W pre-pack ----------------

__global__ void wpack_kernel(const float* __restrict__ conv_w, unsigned int* __restrict__ W2g) {
    int idx = blockIdx.x * 256 + threadIdx.x;
    if (idx < N_CONVS * 16384) {
        int L = idx >> 14;
        int e = idx & 16383;
        int k = e >> 7;
        int n = e & 127;
        float f = conv_w[(size_t)L * 16384 + k * 128 + n];
        W2g[(size_t)L * W2_LAYER + n * W2_STRIDE + k] = pack_hilo(f);
    }
}

// ---------------- MFMA GEMM core macro: split-bf16, 32 rows/wave, fp16 out --------
// a0/a1 frags must be filled by the caller prologue; rest is shared.

#define GEMM_BODY(LOAD_AFRAGS)                                                      \
    __shared__ unsigned int wlds[128 * W2_STRIDE];                                  \
    int t = threadIdx.x;                                                            \
    {                                                                               \
        const uint4* s4 = (const uint4*)W2g;                                        \
        uint4* d4 = (uint4*)wlds;                                                   \
        _Pragma("unroll")                                                           \
        for (int i = 0; i < 17; i++) {                                              \
            int idx = i * 256 + t;                                                  \
            if (idx < (128 * W2_STRIDE) / 4) d4[idx] = s4[idx];                     \
        }                                                                           \
    }                                                                               \
    __syncthreads();                                                                \
    int w = t >> 6;                                                                 \
    int l = t & 63;                                                                 \
    int m = l & 15;                                                                 \
    int q = l >> 4;                                                                 \
    int r0 = blockIdx.x * 128 + w * 32 + m;                                         \
    int r1 = r0 + 16;                                                               \
    int r0c = (r0 > N_NODES - 1) ? (N_NODES - 1) : r0;                              \
    int r1c = (r1 > N_NODES - 1) ? (N_NODES - 1) : r1;                              \
    uint4 a0[8], a1[8];                                                             \
    LOAD_AFRAGS                                                                     \
    f32x4 acc0[8], acc1[8];                                                         \
    _Pragma("unroll")                                                               \
    for (int nb = 0; nb < 8; nb++) {                                                \
        acc0[nb] = (f32x4){0.f, 0.f, 0.f, 0.f};                                     \
        acc1[nb] = (f32x4){0.f, 0.f, 0.f, 0.f};                                     \
    }                                                                               \
    _Pragma("unroll")                                                               \
    for (int nb = 0; nb < 8; nb++) {                                                \
        const unsigned int* wb = &wlds[(nb * 16 + m) * W2_STRIDE];                  \
        _Pragma("unroll")                                                           \
        for (int i = 0; i < 8; i++) {                                               \
            uint4 b = *(const uint4*)(wb + i * 16 + q * 4);                         \
            FragU fa0, fa1, fb, fr;                                                 \
            fa0.u = a0[i]; fa1.u = a1[i]; fb.u = b;                                 \
            acc0[nb] = __builtin_amdgcn_mfma_f32_16x16x32_bf16(fa0.v, fb.v, acc0[nb], 0, 0, 0); \
            acc1[nb] = __builtin_amdgcn_mfma_f32_16x16x32_bf16(fa1.v, fb.v, acc1[nb], 0, 0, 0); \
            fr.u.x = (b.x >> 16) | (b.x << 16);                                     \
            fr.u.y = (b.y >> 16) | (b.y << 16);                                     \
            fr.u.z = (b.z >> 16) | (b.z << 16);                                     \
            fr.u.w = (b.w >> 16) | (b.w << 16);                                     \
            acc0[nb] = __builtin_amdgcn_mfma_f32_16x16x32_bf16(fa0.v, fr.v, acc0[nb], 0, 0, 0); \
            acc1[nb] = __builtin_amdgcn_mfma_f32_16x16x32_bf16(fa1.v, fr.v, acc1[nb], 0, 0, 0); \
        }                                                                           \
    }                                                                               \
    int rbase = blockIdx.x * 128 + w * 32 + q * 4;                                  \
    _Pragma("unroll")                                                               \
    for (int nb = 0; nb < 8; nb++) {                                                \
        _Pragma("unroll")                                                           \
        for (int r = 0; r < 4; r++) {                                               \
            int row = rbase + r;                                                    \
            if (row < N_NODES) Hh[(size_t)row * F + nb * 16 + m] = __float2half(acc0[nb][r]); \
            int row1 = row + 16;                                                    \
            if (row1 < N_NODES) Hh[(size_t)row1 * F + nb * 16 + m] = __float2half(acc1[nb][r]); \
        }                                                                           \
    }

// layer 0: fp32 A input
__global__ __launch_bounds__(256, 2) void gemm_mfma_f32(const float* __restrict__ X,
                                                        const unsigned int* __restrict__ W2g,
                                                        __half* __restrict__ Hh) {
    GEMM_BODY(
        const float4* X4 = (const float4*)X;
        _Pragma("unroll")
        for (int i = 0; i < 8; i++) {
            float4 xv = X4[(size_t)r0c * 32 + i * 4 + q];
            a0[i].x = pack_hilo(xv.x); a0[i].y = pack_hilo(xv.y);
            a0[i].z = pack_hilo(xv.z); a0[i].w = pack_hilo(xv.w);
            float4 yv = X4[(size_t)r1c * 32 + i * 4 + q];
            a1[i].x = pack_hilo(yv.x); a1[i].y = pack_hilo(yv.y);
            a1[i].z = pack_hilo(yv.z); a1[i].w = pack_hilo(yv.w);
        }
    )
}

// layers 1-3: fp16 A input (uint2 = 4 halves per frag-row-quarter)
__global__ __launch_bounds__(256, 2) void gemm_mfma_f16(const __half* __restrict__ X,
                                                        const unsigned int* __restrict__ W2g,
                                                        __half* __restrict__ Hh) {
    GEMM_BODY(
        const uint2* Xh = (const uint2*)X;
        _Pragma("unroll")
        for (int i = 0; i < 8; i++) {
            HU hu0; hu0.u = Xh[(size_t)r0c * 32 + i * 4 + q];
            float2 f01 = __half22float2(hu0.h[0]);
            float2 f23 = __half22float2(hu0.h[1]);
            a0[i].x = pack_hilo(f01.x); a0[i].y = pack_hilo(f01.y);
            a0[i].z = pack_hilo(f23.x); a0[i].w = pack_hilo(f23.y);
            HU hu1; hu1.u = Xh[(size_t)r1c * 32 + i * 4 + q];
            float2 g01 = __half22float2(hu1.h[0]);
            float2 g23 = __half22float2(hu1.h[1]);
            a1[i].x = pack_hilo(g01.x); a1[i].y = pack_hilo(g01.y);
            a1[i].z = pack_hilo(g23.x); a1[i].w = pack_hilo(g23.y);
        }
    )
}

// ---------------- Dual-node aggregation: 2 nodes per wave, fp16 in/out ----------
// Per iteration the wave issues 4 gathers for node A AND 4 for node B (both
// uint4 = 8 fp16 ch/lane, 16 lanes/row) -> 32 independent gathers in flight per
// wave, 2x the real MLP of one-node waves (degree-capped at ~16). Epilogue:
// slot-reduce both nodes, slot 0 writes both fp16 rows.

__global__ __launch_bounds__(256) void agg_kernel(const uint4* __restrict__ H16,
                                                  const int* __restrict__ rowptr,
                                                  const int2* __restrict__ edges,
                                                  const float* __restrict__ dinv,
                                                  const float4* __restrict__ bias4,
                                                  uint4* __restrict__ Xo16) {
    int wv = threadIdx.x >> 6;
    int nodeA = blockIdx.x * 8 + wv * 2;
    int nodeB = nodeA + 1;
    int lane = threadIdx.x & 63;
    int c16 = lane & 15;
    int slot = lane >> 4;

    int nA = (nodeA > N_NODES - 1) ? (N_NODES - 1) : nodeA;
    int nB = (nodeB > N_NODES - 1) ? (N_NODES - 1) : nodeB;
    int loA = rowptr[nA], hiA = rowptr[nA + 1];
    int loB = rowptr[nB], hiB = rowptr[nB + 1];
    int hA1 = hiA - 1; if (hA1 < 0) hA1 = 0;
    int hB1 = hiB - 1; if (hB1 < 0) hB1 = 0;

    float4 aAL = make_float4(0.f, 0.f, 0.f, 0.f), aAH = aAL;
    float4 aBL = aAL, aBH = aAL;

    int iA = loA + slot, iB = loB + slot;
    while (iA < hiA || iB < hiB) {
        int sA[4], sB[4]; float wA[4], wB[4]; uint4 vA[4], vB[4];
#pragma unroll
        for (int j = 0; j < 4; j++) {
            int ija = iA + 4 * j;
            int cja = (ija < hA1) ? ija : hA1;
            int2 eA = edges[cja];
            sA[j] = eA.x; wA[j] = (ija < hiA) ? __int_as_float(eA.y) : 0.f;
            int ijb = iB + 4 * j;
            int cjb = (ijb < hB1) ? ijb : hB1;
            int2 eB = edges[cjb];
            sB[j] = eB.x; wB[j] = (ijb < hiB) ? __int_as_float(eB.y) : 0.f;
        }
#pragma unroll
        for (int j = 0; j < 4; j++) {
            vA[j] = H16[(size_t)sA[j] * 16 + c16];
            vB[j] = H16[(size_t)sB[j] * 16 + c16];
        }
#pragma unroll
        for (int j = 0; j < 4; j++) {
            HU4 x; float2 p0, p1, p2, p3;
            x.u = vA[j];
            p0 = __half22float2(x.h[0]); p1 = __half22float2(x.h[1]);
            p2 = __half22float2(x.h[2]); p3 = __half22float2(x.h[3]);
            aAL.x = fmaf(wA[j], p0.x, aAL.x); aAL.y = fmaf(wA[j], p0.y, aAL.y);
            aAL.z = fmaf(wA[j], p1.x, aAL.z); aAL.w = fmaf(wA[j], p1.y, aAL.w);
            aAH.x = fmaf(wA[j], p2.x, aAH.x); aAH.y = fmaf(wA[j], p2.y, aAH.y);
            aAH.z = fmaf(wA[j], p3.x, aAH.z); aAH.w = fmaf(wA[j], p3.y, aAH.w);
            x.u = vB[j];
            p0 = __half22float2(x.h[0]); p1 = __half22float2(x.h[1]);
            p2 = __half22float2(x.h[2]); p3 = __half22float2(x.h[3]);
            aBL.x = fmaf(wB[j], p0.x, aBL.x); aBL.y = fmaf(wB[j], p0.y, aBL.y);
            aBL.z = fmaf(wB[j], p1.x, aBL.z); aBL.w = fmaf(wB[j], p1.y, aBL.w);
            aBH.x = fmaf(wB[j], p2.x, aBH.x); aBH.y = fmaf(wB[j], p2.y, aBH.y);
            aBH.z = fmaf(wB[j], p3.x, aBH.z); aBH.w = fmaf(wB[j], p3.y, aBH.w);
        }
        iA += 16; iB += 16;
    }

    aAL = red4(aAL); aAH = red4(aAH);
    aBL = red4(aBL); aBH = red4(aBH);

    if (slot == 0) {
        float4 bL = bias4[c16 * 2];
        float4 bH = bias4[c16 * 2 + 1];
        // node A
        if (nodeA < N_NODES) {
            float dn = dinv[nodeA];
            float sw = 2.0f * dn * dn;
            HU4 x; x.u = H16[(size_t)nodeA * 16 + c16];
            float2 p0 = __half22float2(x.h[0]);
            float2 p1 = __half22float2(x.h[1]);
            float2 p2 = __half22float2(x.h[2]);
            float2 p3 = __half22float2(x.h[3]);
            HU4 o;
            o.h[0] = __floats2half2_rn(fmaxf(fmaf(sw, p0.x, aAL.x) + bL.x, 0.f),
                                       fmaxf(fmaf(sw, p0.y, aAL.y) + bL.y, 0.f));
            o.h[1] = __floats2half2_rn(fmaxf(fmaf(sw, p1.x, aAL.z) + bL.z, 0.f),
                                       fmaxf(fmaf(sw, p1.y, aAL.w) + bL.w, 0.f));
            o.h[2] = __floats2half2_rn(fmaxf(fmaf(sw, p2.x, aAH.x) + bH.x, 0.f),
                                       fmaxf(fmaf(sw, p2.y, aAH.y) + bH.y, 0.f));
            o.h[3] = __floats2half2_rn(fmaxf(fmaf(sw, p3.x, aAH.z) + bH.z, 0.f),
                                       fmaxf(fmaf(sw, p3.y, aAH.w) + bH.w, 0.f));
            Xo16[(size_t)nodeA * 16 + c16] = o.u;
        }
        // node B
        if (nodeB < N_NODES) {
            float dn = dinv[nodeB];
            float sw = 2.0f * dn * dn;
            HU4 x; x.u = H16[(size_t)nodeB * 16 + c16];
            float2 p0 = __half22float2(x.h[0]);
            float2 p1 = __half22float2(x.h[1]);
            float2 p2 = __half22float2(x.h[2]);
            float2 p3 = __half22float2(x.h[3]);
            HU4 o;
            o.h[0] = __floats2half2_rn(fmaxf(fmaf(sw, p0.x, aBL.x) + bL.x, 0.f),
                                       fmaxf(fmaf(sw, p0.y, aBL.y) + bL.y, 0.f));
            o.h[1] = __floats2half2_rn(fmaxf(fmaf(sw, p1.x, aBL.z) + bL.z, 0.f),
                                       fmaxf(fmaf(sw, p1.y, aBL.w) + bL.w, 0.f));
            o.h[2] = __floats2half2_rn(fmaxf(fmaf(sw, p2.x, aBH.x) + bH.x, 0.f),
                                       fmaxf(fmaf(sw, p2.y, aBH.y) + bH.y, 0.f));
            o.h[3] = __floats2half2_rn(fmaxf(fmaf(sw, p3.x, aBH.z) + bH.z, 0.f),
                                       fmaxf(fmaf(sw, p3.y, aBH.w) + bH.w, 0.f));
            Xo16[(size_t)nodeB * 16 + c16] = o.u;
        }
    }
}

// ---------------- Fused mean-pool + FC1(relu) + FC2 (fp16 x) ----------------

__global__ __launch_bounds__(256) void pool_fc_kernel(const __half* __restrict__ x,
                                                      const int* __restrict__ batch,
                                                      const float* __restrict__ fc1w,
                                                      const float* __restrict__ fc1b,
                                                      const float* __restrict__ fc2w,
                                                      const float* __restrict__ fc2b,
                                                      float* __restrict__ out) {
    __shared__ float part[2][F];
    __shared__ float pooled[F];
    __shared__ int bnd[2];
    __shared__ float red[2];
    int g = blockIdx.x, t = threadIdx.x;
    int c = t & 127, hlf = t >> 7;

    if (t < 2) {
        int target = g + t;
        int lo = 0, hi = N_NODES;
        while (lo < hi) {
            int m = (lo + hi) >> 1;
            if (batch[m] < target) lo = m + 1;
            else hi = m;
        }
        bnd[t] = lo;
    }
    __syncthreads();
    int lo = bnd[0], hi = bnd[1];

    float s = 0.f;
    int n = lo + hlf;
    for (; n + 6 < hi; n += 8) {
        float v0 = __half2float(x[(size_t)n * F + c]);
        float v1 = __half2float(x[(size_t)(n + 2) * F + c]);
        float v2 = __half2float(x[(size_t)(n + 4) * F + c]);
        float v3 = __half2float(x[(size_t)(n + 6) * F + c]);
        s += (v0 + v1) + (v2 + v3);
    }
    for (; n < hi; n += 2) s += __half2float(x[(size_t)n * F + c]);
    part[hlf][c] = s;
    __syncthreads();

    if (t < F) {
        float cntf = fmaxf((float)(hi - lo), 1.0f);
        pooled[c] = (part[0][c] + part[1][c]) / cntf;
    }
    __syncthreads();

    if (t < F) {
        float acc = fc1b[t];
#pragma unroll 4
        for (int k = 0; k < F; k++) acc = fmaf(pooled[k], fc1w[k * F + t], acc);
        acc = fmaxf(acc, 0.f);

        float p = acc * fc2w[t];
#pragma unroll
        for (int o = 32; o > 0; o >>= 1) p += __shfl_down(p, o, 64);
        if ((t & 63) == 0) red[t >> 6] = p;
    }
    __syncthreads();
    if (t == 0) out[g] = red[0] + red[1] + fc2b[0];
}

// ---------------- launch ----------------

extern "C" void kernel_launch(void* const* d_in, const int* in_sizes, int n_in,
                              void* d_out, int out_size, void* d_ws, size_t ws_size,
                              hipStream_t stream) {
    const float* x_in   = (const float*)d_in[0];
    const int*   eidx   = (const int*)d_in[1];
    const int*   batch  = (const int*)d_in[2];
    const float* conv_w = (const float*)d_in[4];
    const float* conv_b = (const float*)d_in[5];
    const float* fc1w   = (const float*)d_in[6];
    const float* fc1b   = (const float*)d_in[7];
    const float* fc2w   = (const float*)d_in[8];
    const float* fc2b   = (const float*)d_in[9];
    float* out = (float*)d_out;

    const int* src = eidx;
    const int* dst = eidx + N_EDGES;

    char* ws = (char*)d_ws;
    size_t off = 0;
    auto alloc = [&](size_t bytes) -> char* {
        char* p = ws + off;
        off += (bytes + 255) & ~(size_t)255;
        return p;
    };
    __half* bufX  = (__half*)alloc((size_t)N_NODES * F * 2);   // 25.6 MB fp16 (agg out)
    __half* bufH  = (__half*)alloc((size_t)N_NODES * F * 2);   // 25.6 MB fp16 (gemm out)
    float*  dinv  = (float*)alloc((size_t)N_NODES * 4);
    int*    cnt   = (int*)alloc((size_t)N_NODES * 4);
    int*    rowp  = (int*)alloc((size_t)(N_NODES + 1) * 4);
    int*    fill  = (int*)alloc((size_t)N_NODES * 4);
    int2*   edges = (int2*)alloc((size_t)N_EDGES * 8);         // 12.8 MB packed
    unsigned int* W2g = (unsigned int*)alloc((size_t)N_CONVS * W2_LAYER * 4);  // 264 KB
    int*    blks  = (int*)alloc(128 * 4);
    (void)ws_size; (void)in_sizes; (void)n_in; (void)out_size;

    // --- CSR prep + W pre-pack ---
    hipMemsetAsync(cnt, 0, (size_t)N_NODES * 4, stream);
    count_kernel<<<(N_EDGES + 255) / 256, 256, 0, stream>>>(dst, cnt);
    dinv_kernel<<<(N_NODES + 255) / 256, 256, 0, stream>>>(cnt, dinv);
    scan1_kernel<<<SCAN_NBLK, 256, 0, stream>>>(cnt, rowp, blks);
    scan2_kernel<<<1, 128, 0, stream>>>(blks, SCAN_NBLK);
    scan3_kernel<<<SCAN_NBLK, 256, 0, stream>>>(rowp, blks, fill);
    wpack_kernel<<<(N_CONVS * 16384 + 255) / 256, 256, 0, stream>>>(conv_w, W2g);

    // --- windowed CSR fill ---
    fillw_kernel<<<FILL_BLOCKS * NWIN, 256, 0, stream>>>(src, dst, dinv, fill, edges);

    // --- 4 GCN layers: MFMA GEMM + dual-node gather agg (all fp16 buffers) ---
    gemm_mfma_f32<<<(N_NODES + 127) / 128, 256, 0, stream>>>(x_in, W2g, bufH);
    agg_kernel<<<(N_NODES + 7) / 8, 256, 0, stream>>>(
        (const uint4*)bufH, rowp, edges, dinv,
        (const float4*)conv_b, (uint4*)bufX);
    for (int L = 1; L < N_CONVS; L++) {
        gemm_mfma_f16<<<(N_NODES + 127) / 128, 256, 0, stream>>>(
            bufX, W2g + (size_t)L * W2_LAYER, bufH);
        agg_kernel<<<(N_NODES + 7) / 8, 256, 0, stream>>>(
            (const uint4*)bufH, rowp, edges, dinv,
            (const float4*)(conv_b + (size_t)L * F), (uint4*)bufX);
    }

    // --- mean-pool + FC head ---
    pool_fc_kernel<<<N_GRAPHS, 256, 0, stream>>>(bufX, batch, fc1w, fc1b, fc2w, fc2b, out);
}